// Round 4
// baseline (353.133 us; speedup 1.0000x reference)
//
#include <hip/hip_runtime.h>
#include <hip/hip_bf16.h>

#define DF 128
#define BSH 4                 // bucket = dst >> 4  (16 nodes / bucket)
#define BNODES 16
#define NBMAX 4096            // max buckets (50000/16 = 3125)
#define CHUNK 2048            // edges per hist/bin block (fat grids: 391 blocks)
#define BMAX 512              // max edge chunks (391 here)
#define TILE 1024             // edges per aggregation LDS tile (bucket ~256)
#define ASTRIDE 68            // uints per abuf row (64 data + 4 pad)
#define SRCMASK 0x07ffffffu   // src in low 27 bits, dstLocal in bits 27..30

typedef __attribute__((ext_vector_type(8))) short short8;
typedef __attribute__((ext_vector_type(4))) float floatx4;

__device__ __forceinline__ ushort f2bf(float f) {
    __hip_bfloat16 h = __float2bfloat16(f);   // RNE
    return *reinterpret_cast<ushort*>(&h);
}

// ---------------------------------------------------------------------------
// K1: [0,B_) hist blocks | [B_,B_+64) weight convert (+ zero scan-done) |
// rest x convert.  histG layout: [block][bucket] (block-major -> flat scan
// gives each bin block a contiguous output region).
// ---------------------------------------------------------------------------
__global__ __launch_bounds__(256) void prep_kernel(
    const float* __restrict__ x, ushort* __restrict__ xbf, int n4,
    const float* __restrict__ W1, const float* __restrict__ W2,
    const float* __restrict__ b1, const float* __restrict__ b2,
    ushort* __restrict__ w1bf, ushort* __restrict__ w2bf, float* __restrict__ bias,
    const int* __restrict__ dst, int* __restrict__ histG, int* __restrict__ sdone,
    int n_edges, int B_, int nb)
{
    __shared__ int h[NBMAX];
    int bid = blockIdx.x;
    if (bid < B_) {
        for (int j = threadIdx.x; j < nb; j += 256) h[j] = 0;
        __syncthreads();
        int base = bid * CHUNK;
#pragma unroll
        for (int i = 0; i < CHUNK / 256; ++i) {
            int e = base + i * 256 + threadIdx.x;
            if (e < n_edges) atomicAdd(&h[dst[e] >> BSH], 1);
        }
        __syncthreads();
        for (int j = threadIdx.x; j < nb; j += 256)
            histG[bid * nb + j] = h[j];
    } else if (bid < B_ + 64) {
        int i = (bid - B_) * 256 + threadIdx.x;
        if (i < DF * DF) {
            w1bf[i] = f2bf(W1[i]);
            w2bf[i] = f2bf(W2[i]);
        }
        if (i < DF) bias[i] = b1[i] + b2[i];
        if (bid == B_ && threadIdx.x == 0) *sdone = 0;
    } else {
        int i = (bid - B_ - 64) * 256 + threadIdx.x;
        if (i < n4) {
            float4 v = reinterpret_cast<const float4*>(x)[i];
            ushort4 o;
            o.x = f2bf(v.x); o.y = f2bf(v.y); o.z = f2bf(v.z); o.w = f2bf(v.w);
            reinterpret_cast<ushort4*>(xbf)[i] = o;
        }
    }
}

// ---------------------------------------------------------------------------
// K2: hierarchical exclusive scan over histG (flat, block-major).
// Writes: histS (linear, for bin), offsT[bucket][chunk] (transposed scatter,
// for agg's coalesced run load), bsum (per-1024-chunk totals; rewritten to
// exclusive bases by last-finishing block via done-counter).
// final_offs(idx) = histS/offsT-value + bsum[idx>>10].
// ---------------------------------------------------------------------------
__global__ __launch_bounds__(256) void scan_kernel(
    const int* __restrict__ cnt, int* __restrict__ offs, int* __restrict__ offsT,
    int* __restrict__ bsum, int* __restrict__ sdone,
    int n, int nb2, int nb, int B_)
{
    __shared__ int sd[256];
    __shared__ int isLast;
    int t = threadIdx.x;
    int base = blockIdx.x * 1024 + t * 4;

    int4 v = make_int4(0, 0, 0, 0);
    if (base + 3 < n) {
        v = *reinterpret_cast<const int4*>(cnt + base);
    } else {
        if (base + 0 < n) v.x = cnt[base + 0];
        if (base + 1 < n) v.y = cnt[base + 1];
        if (base + 2 < n) v.z = cnt[base + 2];
        if (base + 3 < n) v.w = cnt[base + 3];
    }
    int s = v.x + v.y + v.z + v.w;
    sd[t] = s;
    __syncthreads();
    for (int off = 1; off < 256; off <<= 1) {
        int u = (t >= off) ? sd[t - off] : 0;
        __syncthreads();
        sd[t] += u;
        __syncthreads();
    }
    int incl = sd[t];
    int excl = incl - s;
    if (t == 255) bsum[blockIdx.x] = incl;

    int p[4];
    p[0] = excl; p[1] = p[0] + v.x; p[2] = p[1] + v.y; p[3] = p[2] + v.z;
#pragma unroll
    for (int k = 0; k < 4; ++k) {
        int f = base + k;
        if (f < n) {
            offs[f] = p[k];
            int b = f / nb;               // chunk index
            int j = f - b * nb;           // bucket index
            offsT[(size_t)j * B_ + b] = p[k];
            if (j == 0 && b > 0)          // also serves as end-row (bucket nb)
                offsT[(size_t)nb * B_ + (b - 1)] = p[k];
        }
    }

    // fused exclusive scan of bsum[0..nb2) by the last-finishing block
    __threadfence();
    __syncthreads();
    if (t == 0) isLast = (atomicAdd(sdone, 1) == gridDim.x - 1);
    __syncthreads();
    if (isLast) {
        int b0 = t * 8;
        int tv[8];
        int ls = 0;
#pragma unroll
        for (int k = 0; k < 8; ++k) {
            int idx = b0 + k;
            int u = (idx < nb2)
                ? __hip_atomic_load(&bsum[idx], __ATOMIC_RELAXED,
                                    __HIP_MEMORY_SCOPE_AGENT)
                : 0;
            tv[k] = u; ls += u;
        }
        sd[t] = ls;
        __syncthreads();
        for (int off = 1; off < 256; off <<= 1) {
            int u = (t >= off) ? sd[t - off] : 0;
            __syncthreads();
            sd[t] += u;
            __syncthreads();
        }
        int run = sd[t] - ls;
#pragma unroll
        for (int k = 0; k < 8; ++k) {
            int idx = b0 + k;
            if (idx < nb2) bsum[idx] = run;
            run += tv[k];
        }
    }
}

// ---------------------------------------------------------------------------
// K3: bin. Sort this block's CHUNK edges by bucket into LDS, then write its
// OWN CONTIGUOUS region [blk*CHUNK, blk*CHUNK+cnt) with coalesced stores.
// pairs[p] = src | dstLocal<<27.  391 blocks (fat grid).
// ---------------------------------------------------------------------------
__global__ __launch_bounds__(256) void bin_kernel(
    const int* __restrict__ src, const int* __restrict__ dst,
    const int* __restrict__ histS, const int* __restrict__ bsum,
    uint* __restrict__ pairs, int n_edges, int B_, int nb)
{
    __shared__ int  cur[NBMAX];     // 16 KB global cursors
    __shared__ uint stage[CHUNK];   // 8 KB
    int blk = blockIdx.x;
    for (int j = threadIdx.x; j < nb; j += 256) {
        int idx = blk * nb + j;
        cur[j] = histS[idx] + bsum[idx >> 10];
    }
    __syncthreads();
    int base = blk * CHUNK;
    int cnt = n_edges - base; if (cnt > CHUNK) cnt = CHUNK;
    for (int i = threadIdx.x; i < cnt; i += 256) {
        int e = base + i;
        int d = dst[e];
        int j = d >> BSH;
        int p = atomicAdd(&cur[j], 1);
        stage[p - base] = (uint)src[e] | ((uint)(d & (BNODES - 1)) << 27);
    }
    __syncthreads();
    for (int i = threadIdx.x; i < cnt; i += 256)
        pairs[base + i] = stage[i];
}

// ---------------------------------------------------------------------------
// K4: fused aggregate + MFMA GEMM. Block = 16 nodes = 1 bucket, 256 threads,
// 3125 blocks, 8 blocks/CU resident. Run table loaded via transposed offsT
// (two coalesced rows). Wave owns 4 nodes; 16-deep gather.
// ---------------------------------------------------------------------------
__global__ __launch_bounds__(256, 8) void agg_gemm_kernel(
    const ushort* __restrict__ xbf, const uint* __restrict__ pairs,
    const int* __restrict__ offsT, const int* __restrict__ bsum,
    const ushort* __restrict__ w1, const ushort* __restrict__ w2,
    const float* __restrict__ bias, float* __restrict__ out,
    int n_nodes, int n_edges, int B_, int nb, int flat)
{
    __shared__ uint sorted[TILE];               // 4 KB (byte offsets, src<<8)
    __shared__ uint abuf[BNODES * ASTRIDE];     // 4.35 KB
    __shared__ int  rstart[BMAX];
    __shared__ int  rexcl[BMAX + 1];
    __shared__ int hcnt[BNODES];
    __shared__ int hoff[BNODES + 1];
    __shared__ int hcur[BNODES];

    int blk  = blockIdx.x;      // == bucket index
    int node0 = blk * BNODES;
    int wave = threadIdx.x >> 6;
    int lane = threadIdx.x & 63;

    // runs: chunk j's cell for this bucket; coalesced via transposed rows
    for (int j = threadIdx.x; j < B_; j += 256) {
        int s = offsT[(size_t)blk * B_ + j] + bsum[(j * nb + blk) >> 10];
        int idx2 = j * nb + blk + 1;
        int e = (idx2 >= flat) ? n_edges
                               : offsT[(size_t)(blk + 1) * B_ + j] + bsum[idx2 >> 10];
        rstart[j] = s;
        rexcl[j]  = e - s;     // count (temp)
    }
    __syncthreads();
    if (threadIdx.x < 64) {     // wave 0: exclusive scan of <=512 counts
        int b0 = lane * 8;
        int tv[8];
        int ls = 0;
#pragma unroll
        for (int k = 0; k < 8; ++k) {
            int idx = b0 + k;
            tv[k] = (idx < B_) ? rexcl[idx] : 0;
            ls += tv[k];
        }
        int si = ls;
#pragma unroll
        for (int off = 1; off < 64; off <<= 1) {
            int u = __shfl_up(si, off);
            if (lane >= off) si += u;
        }
        int run = si - ls;
#pragma unroll
        for (int k = 0; k < 8; ++k) {
            int idx = b0 + k;
            if (idx < B_) rexcl[idx] = run;
            run += tv[k];
        }
        if (lane == 63) rexcl[B_] = run;   // total
    }
    __syncthreads();
    int total = rexcl[B_];

    const char* xu = (const char*)xbf;
    uint lane4 = (uint)lane << 2;

    float2 acc[4];
#pragma unroll
    for (int i = 0; i < 4; ++i) acc[i] = make_float2(0.f, 0.f);

    for (int t0 = 0; t0 < total; t0 += TILE) {
        int cnt = total - t0; if (cnt > TILE) cnt = TILE;

        if (threadIdx.x < BNODES) hcnt[threadIdx.x] = 0;
        __syncthreads();

        // pass A: binary-search run, read pair into registers, node-histogram
        uint pk_[TILE / 256];
#pragma unroll
        for (int k = 0; k < TILE / 256; ++k) {
            int i = threadIdx.x + k * 256;
            if (i < cnt) {
                int t = t0 + i;
                int lo = 0, hi = B_;
                while (lo + 1 < hi) {
                    int mid = (lo + hi) >> 1;
                    if (rexcl[mid] <= t) lo = mid; else hi = mid;
                }
                uint pk = pairs[rstart[lo] + (t - rexcl[lo])];
                pk_[k] = pk;
                atomicAdd(&hcnt[pk >> 27], 1);
            }
        }
        __syncthreads();

        // 16-entry exclusive scan by wave 0 via shfl
        if (threadIdx.x < 64) {
            int v = (lane < BNODES) ? hcnt[lane] : 0;
#pragma unroll
            for (int off = 1; off < BNODES; off <<= 1) {
                int u = __shfl_up(v, off);
                if (lane >= off) v += u;
            }
            if (lane < BNODES) {
                hoff[lane + 1] = v;
                hcur[lane] = v - hcnt[lane];
            }
            if (lane == 0) hoff[0] = 0;
        }
        __syncthreads();

        // pass B: scatter pre-scaled row byte-offsets, node-sorted
#pragma unroll
        for (int k = 0; k < TILE / 256; ++k) {
            int i = threadIdx.x + k * 256;
            if (i < cnt) {
                uint pk = pk_[k];
                int p = atomicAdd(&hcur[pk >> 27], 1);
                sorted[p] = (pk & SRCMASK) << 8;   // byte offset of 256B row
            }
        }
        __syncthreads();

        // wave owns nodes wave*4 .. wave*4+3; 16-deep independent gathers
#pragma unroll
        for (int i = 0; i < 4; ++i) {
            int nl = wave * 4 + i;
            int j0 = hoff[nl], j1 = hoff[nl + 1];
            float2 a = acc[i];
            int j = j0;
            for (; j + 15 < j1; j += 16) {
                uint u[16];
#pragma unroll
                for (int k = 0; k < 16; ++k)
                    u[k] = *(const uint*)(xu + (size_t)(sorted[j + k] + lane4));
#pragma unroll
                for (int k = 0; k < 16; ++k) {
                    a.x += __uint_as_float(u[k] << 16);
                    a.y += __uint_as_float(u[k] & 0xffff0000u);
                }
            }
            for (; j + 3 < j1; j += 4) {
                uint u0 = *(const uint*)(xu + (size_t)(sorted[j + 0] + lane4));
                uint u1 = *(const uint*)(xu + (size_t)(sorted[j + 1] + lane4));
                uint u2 = *(const uint*)(xu + (size_t)(sorted[j + 2] + lane4));
                uint u3 = *(const uint*)(xu + (size_t)(sorted[j + 3] + lane4));
                a.x += __uint_as_float(u0 << 16) + __uint_as_float(u1 << 16)
                     + __uint_as_float(u2 << 16) + __uint_as_float(u3 << 16);
                a.y += __uint_as_float(u0 & 0xffff0000u) + __uint_as_float(u1 & 0xffff0000u)
                     + __uint_as_float(u2 & 0xffff0000u) + __uint_as_float(u3 & 0xffff0000u);
            }
            for (; j < j1; ++j) {
                uint u = *(const uint*)(xu + (size_t)(sorted[j] + lane4));
                a.x += __uint_as_float(u << 16);
                a.y += __uint_as_float(u & 0xffff0000u);
            }
            acc[i] = a;
        }
        __syncthreads();   // protect sorted/hist before next tile
    }

    // stage aggregated rows as bf16 into LDS (row stride 68 uints)
#pragma unroll
    for (int i = 0; i < 4; ++i) {
        int nl = wave * 4 + i;
        abuf[nl * ASTRIDE + lane] =
            (uint)f2bf(acc[i].x) | ((uint)f2bf(acc[i].y) << 16);
    }
    __syncthreads();

    // ---- MFMA phase: 16 rows; wave w does o-tiles w*2, w*2+1 ----
    int quad = lane >> 4;
    int m    = lane & 15;
    int rowG = node0 + m;
    int rowC = (rowG < n_nodes) ? rowG : (n_nodes - 1);   // clamp loads

    short8 xa[4], aa[4];
#pragma unroll
    for (int ks = 0; ks < 4; ++ks) {
        xa[ks] = *reinterpret_cast<const short8*>(xbf + (size_t)rowC * DF + ks * 32 + quad * 8);
        aa[ks] = *reinterpret_cast<const short8*>(&abuf[m * ASTRIDE + ks * 16 + quad * 4]);
    }

#pragma unroll
    for (int oi = 0; oi < 2; ++oi) {
        int ot = wave * 2 + oi;
        int o = ot * 16 + m;
        floatx4 c = {0.f, 0.f, 0.f, 0.f};
#pragma unroll
        for (int ks = 0; ks < 4; ++ks) {
            short8 bf1 = *reinterpret_cast<const short8*>(w1 + (size_t)o * DF + ks * 32 + quad * 8);
            short8 bf2 = *reinterpret_cast<const short8*>(w2 + (size_t)o * DF + ks * 32 + quad * 8);
            c = __builtin_amdgcn_mfma_f32_16x16x32_bf16(xa[ks], bf1, c, 0, 0, 0);
            c = __builtin_amdgcn_mfma_f32_16x16x32_bf16(aa[ks], bf2, c, 0, 0, 0);
        }
        float bv = bias[o];
#pragma unroll
        for (int r = 0; r < 4; ++r) {
            int row = node0 + quad * 4 + r;
            if (row < n_nodes) out[(size_t)row * DF + o] = c[r] + bv;
        }
    }
}

extern "C" void kernel_launch(void* const* d_in, const int* in_sizes, int n_in,
                              void* d_out, int out_size, void* d_ws, size_t ws_size,
                              hipStream_t stream) {
    const float* x  = (const float*)d_in[0];
    const float* W1 = (const float*)d_in[1];
    const float* b1 = (const float*)d_in[2];
    const float* W2 = (const float*)d_in[3];
    const float* b2 = (const float*)d_in[4];
    const int* esrc = (const int*)d_in[5];
    const int* edst = (const int*)d_in[6];
    float* out = (float*)d_out;

    int n_nodes = in_sizes[0] / DF;
    int n_edges = in_sizes[5];

    int nb = (n_nodes + BNODES - 1) >> BSH;       // buckets (3125)
    int B_ = (n_edges + CHUNK - 1) / CHUNK;       // edge chunks (391 <= BMAX)
    int flat = nb * B_;                           // hist matrix size (~1.22M)

    char* ws = (char*)d_ws;
    ushort* xbf   = (ushort*)ws;                 ws += (size_t)n_nodes * DF * 2;
    ushort* w1bf  = (ushort*)ws;                 ws += (size_t)DF * DF * 2;
    ushort* w2bf  = (ushort*)ws;                 ws += (size_t)DF * DF * 2;
    float*  bias  = (float*)ws;                  ws += (size_t)DF * 4;
    int*    histG = (int*)ws;                    ws += (size_t)flat * 4;
    int*    histS = (int*)ws;                    ws += (size_t)(flat + 1) * 4;
    int*    offsT = (int*)ws;                    ws += (size_t)(nb + 1) * B_ * 4;
    int*    bsum  = (int*)ws;                    ws += 2048 * 4;
    int*    sdone = (int*)ws;                    ws += 4;
    uint*   pairs = (uint*)ws;

    int n4 = n_nodes * DF / 4;
    int prep_blocks = B_ + 64 + (n4 + 255) / 256;
    prep_kernel<<<prep_blocks, 256, 0, stream>>>(
        x, xbf, n4, W1, W2, b1, b2, w1bf, w2bf, bias,
        edst, histG, sdone, n_edges, B_, nb);

    int nb2 = (flat + 1023) / 1024;
    scan_kernel<<<nb2, 256, 0, stream>>>(histG, histS, offsT, bsum, sdone,
                                         flat, nb2, nb, B_);

    bin_kernel<<<B_, 256, 0, stream>>>(esrc, edst, histS, bsum, pairs, n_edges, B_, nb);

    agg_gemm_kernel<<<nb, 256, 0, stream>>>(
        xbf, pairs, offsT, bsum, w1bf, w2bf, bias, out,
        n_nodes, n_edges, B_, nb, flat);
}

// Round 5
// 227.708 us; speedup vs baseline: 1.5508x; 1.5508x over previous
//
#include <hip/hip_runtime.h>
#include <hip/hip_bf16.h>

#define DF 128
#define BSH 5                 // bucket = dst >> 5  (32 nodes / bucket)
#define BNODES 32
#define NBMAX 1600            // max buckets (50000/32 = 1563)
#define CHUNK 2048            // edges per hist/bin block (fat grids: 391 blocks)
#define BMAX 400              // max edge chunks (391 here)
#define TILE 2048             // edges per aggregation LDS tile (bucket ~512)
#define ASTRIDE 64            // uints per abuf row
#define SRCMASK 0x07ffffffu   // src in low 27 bits, dstLocal in bits 27..31

typedef __attribute__((ext_vector_type(8))) short short8;
typedef __attribute__((ext_vector_type(4))) float floatx4;

__device__ __forceinline__ ushort f2bf(float f) {
    __hip_bfloat16 h = __float2bfloat16(f);   // RNE
    return *reinterpret_cast<ushort*>(&h);
}

// ---------------------------------------------------------------------------
// K1: [0,B_) hist blocks | [B_,B_+64) weight convert (+ zero scan-done) |
// rest x convert.  histG layout: [block][bucket] (block-major -> flat scan
// gives each bin block a contiguous output region).  All writes coalesced.
// ---------------------------------------------------------------------------
__global__ __launch_bounds__(256) void prep_kernel(
    const float* __restrict__ x, ushort* __restrict__ xbf, int n4,
    const float* __restrict__ W1, const float* __restrict__ W2,
    const float* __restrict__ b1, const float* __restrict__ b2,
    ushort* __restrict__ w1bf, ushort* __restrict__ w2bf, float* __restrict__ bias,
    const int* __restrict__ dst, int* __restrict__ histG, int* __restrict__ sdone,
    int n_edges, int B_, int nb)
{
    __shared__ int h[NBMAX];
    int bid = blockIdx.x;
    if (bid < B_) {
        for (int j = threadIdx.x; j < nb; j += 256) h[j] = 0;
        __syncthreads();
        int base = bid * CHUNK;
#pragma unroll
        for (int i = 0; i < CHUNK / 256; ++i) {
            int e = base + i * 256 + threadIdx.x;
            if (e < n_edges) atomicAdd(&h[dst[e] >> BSH], 1);
        }
        __syncthreads();
        for (int j = threadIdx.x; j < nb; j += 256)
            histG[bid * nb + j] = h[j];
    } else if (bid < B_ + 64) {
        int i = (bid - B_) * 256 + threadIdx.x;
        if (i < DF * DF) {
            w1bf[i] = f2bf(W1[i]);
            w2bf[i] = f2bf(W2[i]);
        }
        if (i < DF) bias[i] = b1[i] + b2[i];
        if (bid == B_ && threadIdx.x == 0) *sdone = 0;
    } else {
        int i = (bid - B_ - 64) * 256 + threadIdx.x;
        if (i < n4) {
            float4 v = reinterpret_cast<const float4*>(x)[i];
            ushort4 o;
            o.x = f2bf(v.x); o.y = f2bf(v.y); o.z = f2bf(v.z); o.w = f2bf(v.w);
            reinterpret_cast<ushort4*>(xbf)[i] = o;
        }
    }
}

// ---------------------------------------------------------------------------
// K2: hierarchical exclusive scan over histG (flat, block-major), all linear.
// bsum per-1024 totals; rewritten to exclusive bases by last-finishing block.
// final_offs(idx) = histS[idx] + bsum[idx>>10].
// ---------------------------------------------------------------------------
__global__ __launch_bounds__(256) void scan_kernel(
    const int* __restrict__ cnt, int* __restrict__ offs,
    int* __restrict__ bsum, int* __restrict__ sdone, int n, int nb2)
{
    __shared__ int sd[256];
    __shared__ int isLast;
    int t = threadIdx.x;
    int base = blockIdx.x * 1024 + t * 4;

    int4 v = make_int4(0, 0, 0, 0);
    if (base + 3 < n) {
        v = *reinterpret_cast<const int4*>(cnt + base);
    } else {
        if (base + 0 < n) v.x = cnt[base + 0];
        if (base + 1 < n) v.y = cnt[base + 1];
        if (base + 2 < n) v.z = cnt[base + 2];
        if (base + 3 < n) v.w = cnt[base + 3];
    }
    int s = v.x + v.y + v.z + v.w;
    sd[t] = s;
    __syncthreads();
    for (int off = 1; off < 256; off <<= 1) {
        int u = (t >= off) ? sd[t - off] : 0;
        __syncthreads();
        sd[t] += u;
        __syncthreads();
    }
    int incl = sd[t];
    int excl = incl - s;
    if (t == 255) bsum[blockIdx.x] = incl;

    int p0 = excl, p1 = p0 + v.x, p2 = p1 + v.y, p3 = p2 + v.z;
    if (base + 0 < n) offs[base + 0] = p0;
    if (base + 1 < n) offs[base + 1] = p1;
    if (base + 2 < n) offs[base + 2] = p2;
    if (base + 3 < n) offs[base + 3] = p3;

    // fused exclusive scan of bsum[0..nb2) by the last-finishing block
    __threadfence();
    __syncthreads();
    if (t == 0) isLast = (atomicAdd(sdone, 1) == gridDim.x - 1);
    __syncthreads();
    if (isLast) {
        int b0 = t * 8;
        int tv[8];
        int ls = 0;
#pragma unroll
        for (int k = 0; k < 8; ++k) {
            int idx = b0 + k;
            int u = (idx < nb2)
                ? __hip_atomic_load(&bsum[idx], __ATOMIC_RELAXED,
                                    __HIP_MEMORY_SCOPE_AGENT)
                : 0;
            tv[k] = u; ls += u;
        }
        sd[t] = ls;
        __syncthreads();
        for (int off = 1; off < 256; off <<= 1) {
            int u = (t >= off) ? sd[t - off] : 0;
            __syncthreads();
            sd[t] += u;
            __syncthreads();
        }
        int run = sd[t] - ls;
#pragma unroll
        for (int k = 0; k < 8; ++k) {
            int idx = b0 + k;
            if (idx < nb2) bsum[idx] = run;
            run += tv[k];
        }
    }
}

// ---------------------------------------------------------------------------
// K3: bin. Sort this block's CHUNK edges by bucket into LDS, then write its
// OWN CONTIGUOUS region [blk*CHUNK, blk*CHUNK+cnt) with coalesced stores.
// pairs[p] = src | dstLocal<<27.  391 blocks (fat grid), small LDS.
// ---------------------------------------------------------------------------
__global__ __launch_bounds__(256) void bin_kernel(
    const int* __restrict__ src, const int* __restrict__ dst,
    const int* __restrict__ histS, const int* __restrict__ bsum,
    uint* __restrict__ pairs, int n_edges, int B_, int nb)
{
    __shared__ int  cur[NBMAX];     // 6.4 KB global cursors
    __shared__ uint stage[CHUNK];   // 8 KB
    int blk = blockIdx.x;
    for (int j = threadIdx.x; j < nb; j += 256) {
        int idx = blk * nb + j;
        cur[j] = histS[idx] + bsum[idx >> 10];
    }
    __syncthreads();
    int base = blk * CHUNK;
    int cnt = n_edges - base; if (cnt > CHUNK) cnt = CHUNK;
    for (int i = threadIdx.x; i < cnt; i += 256) {
        int e = base + i;
        int d = dst[e];
        int j = d >> BSH;
        int p = atomicAdd(&cur[j], 1);
        stage[p - base] = (uint)src[e] | ((uint)(d & (BNODES - 1)) << 27);
    }
    __syncthreads();
    for (int i = threadIdx.x; i < cnt; i += 256)
        pairs[base + i] = stage[i];
}

// ---------------------------------------------------------------------------
// K4: fused aggregate + MFMA GEMM. Block = 32 nodes = 1 bucket, 256 threads,
// 1563 blocks, 8 blocks/CU (19.9 KB LDS). Runs located via 9-step binary
// search over 391 scanned counts. Wave owns 8 nodes; 16-deep gather.
// ---------------------------------------------------------------------------
__global__ __launch_bounds__(256, 8) void agg_gemm_kernel(
    const ushort* __restrict__ xbf, const uint* __restrict__ pairs,
    const int* __restrict__ histS, const int* __restrict__ bsum,
    const ushort* __restrict__ w1, const ushort* __restrict__ w2,
    const float* __restrict__ bias, float* __restrict__ out,
    int n_nodes, int n_edges, int B_, int nb, int flat)
{
    __shared__ uint sorted[TILE];               // 8 KB (byte offsets, src<<8)
    __shared__ uint abuf[BNODES * ASTRIDE];     // 8 KB
    __shared__ int  rstart[BMAX];               // 1.6 KB
    __shared__ int  rexcl[BMAX + 1];            // 1.6 KB
    __shared__ int hcnt[BNODES];
    __shared__ int hoff[BNODES + 1];
    __shared__ int hcur[BNODES];

    int blk  = blockIdx.x;      // == bucket index
    int node0 = blk * BNODES;
    int wave = threadIdx.x >> 6;
    int lane = threadIdx.x & 63;

    // runs: chunk j's cell for this bucket = [offs(j*nb+blk), offs(j*nb+blk+1))
    for (int j = threadIdx.x; j < B_; j += 256) {
        int idx = j * nb + blk;
        int s = histS[idx] + bsum[idx >> 10];
        int idx2 = idx + 1;
        int e = (idx2 >= flat) ? n_edges : histS[idx2] + bsum[idx2 >> 10];
        rstart[j] = s;
        rexcl[j]  = e - s;     // count (temp)
    }
    __syncthreads();
    if (threadIdx.x < 64) {     // wave 0: exclusive scan of <=448 counts
        int b0 = lane * 7;
        int tv[7];
        int ls = 0;
#pragma unroll
        for (int k = 0; k < 7; ++k) {
            int idx = b0 + k;
            tv[k] = (idx < B_) ? rexcl[idx] : 0;
            ls += tv[k];
        }
        int si = ls;
#pragma unroll
        for (int off = 1; off < 64; off <<= 1) {
            int u = __shfl_up(si, off);
            if (lane >= off) si += u;
        }
        int run = si - ls;
#pragma unroll
        for (int k = 0; k < 7; ++k) {
            int idx = b0 + k;
            if (idx < B_) rexcl[idx] = run;
            run += tv[k];
        }
        if (lane == 63) rexcl[B_] = run;   // total
    }
    __syncthreads();
    int total = rexcl[B_];

    const char* xu = (const char*)xbf;
    uint lane4 = (uint)lane << 2;

    float2 acc[8];
#pragma unroll
    for (int i = 0; i < 8; ++i) acc[i] = make_float2(0.f, 0.f);

    for (int t0 = 0; t0 < total; t0 += TILE) {
        int cnt = total - t0; if (cnt > TILE) cnt = TILE;

        if (threadIdx.x < BNODES) hcnt[threadIdx.x] = 0;
        __syncthreads();

        // pass A: binary-search run, read pair into registers, node-histogram
        uint pk_[TILE / 256];
#pragma unroll
        for (int k = 0; k < TILE / 256; ++k) {
            int i = threadIdx.x + k * 256;
            if (i < cnt) {
                int t = t0 + i;
                int lo = 0, hi = B_;
                while (lo + 1 < hi) {
                    int mid = (lo + hi) >> 1;
                    if (rexcl[mid] <= t) lo = mid; else hi = mid;
                }
                uint pk = pairs[rstart[lo] + (t - rexcl[lo])];
                pk_[k] = pk;
                atomicAdd(&hcnt[pk >> 27], 1);
            }
        }
        __syncthreads();

        // 32-entry exclusive scan by wave 0 via shfl
        if (threadIdx.x < 64) {
            int v = (lane < BNODES) ? hcnt[lane] : 0;
#pragma unroll
            for (int off = 1; off < BNODES; off <<= 1) {
                int u = __shfl_up(v, off);
                if (lane >= off) v += u;
            }
            if (lane < BNODES) {
                hoff[lane + 1] = v;
                hcur[lane] = v - hcnt[lane];
            }
            if (lane == 0) hoff[0] = 0;
        }
        __syncthreads();

        // pass B: scatter pre-scaled row byte-offsets, node-sorted
#pragma unroll
        for (int k = 0; k < TILE / 256; ++k) {
            int i = threadIdx.x + k * 256;
            if (i < cnt) {
                uint pk = pk_[k];
                int p = atomicAdd(&hcur[pk >> 27], 1);
                sorted[p] = (pk & SRCMASK) << 8;   // byte offset of 256B row
            }
        }
        __syncthreads();

        // wave owns nodes wave*8 .. wave*8+7; 16-deep independent gathers
#pragma unroll
        for (int i = 0; i < 8; ++i) {
            int nl = wave * 8 + i;
            int j0 = hoff[nl], j1 = hoff[nl + 1];
            float2 a = acc[i];
            int j = j0;
            for (; j + 15 < j1; j += 16) {
                uint u[16];
#pragma unroll
                for (int k = 0; k < 16; ++k)
                    u[k] = *(const uint*)(xu + (size_t)(sorted[j + k] + lane4));
#pragma unroll
                for (int k = 0; k < 16; ++k) {
                    a.x += __uint_as_float(u[k] << 16);
                    a.y += __uint_as_float(u[k] & 0xffff0000u);
                }
            }
            for (; j + 3 < j1; j += 4) {
                uint u0 = *(const uint*)(xu + (size_t)(sorted[j + 0] + lane4));
                uint u1 = *(const uint*)(xu + (size_t)(sorted[j + 1] + lane4));
                uint u2 = *(const uint*)(xu + (size_t)(sorted[j + 2] + lane4));
                uint u3 = *(const uint*)(xu + (size_t)(sorted[j + 3] + lane4));
                a.x += __uint_as_float(u0 << 16) + __uint_as_float(u1 << 16)
                     + __uint_as_float(u2 << 16) + __uint_as_float(u3 << 16);
                a.y += __uint_as_float(u0 & 0xffff0000u) + __uint_as_float(u1 & 0xffff0000u)
                     + __uint_as_float(u2 & 0xffff0000u) + __uint_as_float(u3 & 0xffff0000u);
            }
            for (; j < j1; ++j) {
                uint u = *(const uint*)(xu + (size_t)(sorted[j] + lane4));
                a.x += __uint_as_float(u << 16);
                a.y += __uint_as_float(u & 0xffff0000u);
            }
            acc[i] = a;
        }
        __syncthreads();   // protect sorted/hist before next tile
    }

    // stage aggregated rows as bf16 into LDS
#pragma unroll
    for (int i = 0; i < 8; ++i) {
        int nl = wave * 8 + i;
        abuf[nl * ASTRIDE + lane] =
            (uint)f2bf(acc[i].x) | ((uint)f2bf(acc[i].y) << 16);
    }
    __syncthreads();

    // ---- MFMA phase: 2 waves per 16-row group; each does 4 of 8 o-tiles ----
    int quad = lane >> 4;
    int m    = lane & 15;
    int rg   = wave >> 1;          // row group 0..1
    int half = wave & 1;           // which 4 o-tiles
    int rowL = rg * 16 + m;
    int rowG = node0 + rowL;
    int rowC = (rowG < n_nodes) ? rowG : (n_nodes - 1);   // clamp loads

    short8 xa[4], aa[4];
#pragma unroll
    for (int ks = 0; ks < 4; ++ks) {
        xa[ks] = *reinterpret_cast<const short8*>(xbf + (size_t)rowC * DF + ks * 32 + quad * 8);
        aa[ks] = *reinterpret_cast<const short8*>(&abuf[rowL * ASTRIDE + ks * 16 + quad * 4]);
    }

    int nbase = node0 + rg * 16;
#pragma unroll
    for (int oi = 0; oi < 4; ++oi) {
        int ot = half * 4 + oi;
        int o = ot * 16 + m;
        floatx4 c = {0.f, 0.f, 0.f, 0.f};
#pragma unroll
        for (int ks = 0; ks < 4; ++ks) {
            short8 bf1 = *reinterpret_cast<const short8*>(w1 + (size_t)o * DF + ks * 32 + quad * 8);
            short8 bf2 = *reinterpret_cast<const short8*>(w2 + (size_t)o * DF + ks * 32 + quad * 8);
            c = __builtin_amdgcn_mfma_f32_16x16x32_bf16(xa[ks], bf1, c, 0, 0, 0);
            c = __builtin_amdgcn_mfma_f32_16x16x32_bf16(aa[ks], bf2, c, 0, 0, 0);
        }
        float bv = bias[o];
#pragma unroll
        for (int r = 0; r < 4; ++r) {
            int row = nbase + quad * 4 + r;
            if (row < n_nodes) out[(size_t)row * DF + o] = c[r] + bv;
        }
    }
}

extern "C" void kernel_launch(void* const* d_in, const int* in_sizes, int n_in,
                              void* d_out, int out_size, void* d_ws, size_t ws_size,
                              hipStream_t stream) {
    const float* x  = (const float*)d_in[0];
    const float* W1 = (const float*)d_in[1];
    const float* b1 = (const float*)d_in[2];
    const float* W2 = (const float*)d_in[3];
    const float* b2 = (const float*)d_in[4];
    const int* esrc = (const int*)d_in[5];
    const int* edst = (const int*)d_in[6];
    float* out = (float*)d_out;

    int n_nodes = in_sizes[0] / DF;
    int n_edges = in_sizes[5];

    int nb = (n_nodes + BNODES - 1) >> BSH;       // buckets (1563)
    int B_ = (n_edges + CHUNK - 1) / CHUNK;       // edge chunks (391 <= BMAX-1)
    int flat = nb * B_;                           // hist matrix size (~611k)

    auto rnd16 = [](size_t v) { return (v + 15) & ~(size_t)15; };

    char* ws = (char*)d_ws;
    ushort* xbf   = (ushort*)ws;                 ws += rnd16((size_t)n_nodes * DF * 2);
    ushort* w1bf  = (ushort*)ws;                 ws += rnd16((size_t)DF * DF * 2);
    ushort* w2bf  = (ushort*)ws;                 ws += rnd16((size_t)DF * DF * 2);
    float*  bias  = (float*)ws;                  ws += rnd16((size_t)DF * 4);
    int*    histG = (int*)ws;                    ws += rnd16((size_t)flat * 4);
    int*    histS = (int*)ws;                    ws += rnd16((size_t)(flat + 1) * 4);
    int*    bsum  = (int*)ws;                    ws += 1024 * 4;
    int*    sdone = (int*)ws;                    ws += 16;
    uint*   pairs = (uint*)ws;

    int n4 = n_nodes * DF / 4;
    int prep_blocks = B_ + 64 + (n4 + 255) / 256;
    prep_kernel<<<prep_blocks, 256, 0, stream>>>(
        x, xbf, n4, W1, W2, b1, b2, w1bf, w2bf, bias,
        edst, histG, sdone, n_edges, B_, nb);

    int nb2 = (flat + 1023) / 1024;
    scan_kernel<<<nb2, 256, 0, stream>>>(histG, histS, bsum, sdone, flat, nb2);

    bin_kernel<<<B_, 256, 0, stream>>>(esrc, edst, histS, bsum, pairs, n_edges, B_, nb);

    agg_gemm_kernel<<<nb, 256, 0, stream>>>(
        xbf, pairs, histS, bsum, w1bf, w2bf, bias, out,
        n_nodes, n_edges, B_, nb, flat);
}

// Round 6
// 165.746 us; speedup vs baseline: 2.1306x; 1.3738x over previous
//
#include <hip/hip_runtime.h>
#include <hip/hip_bf16.h>

#define DF 128
#define BSH 5                 // bucket = dst >> 5  (32 nodes / bucket)
#define BNODES 32
#define NBMAX 1600            // max buckets (50000/32 = 1563)
#define CHUNK 2048            // edges per hist/bin block (fat grids: 391 blocks)
#define BMAX 400              // max edge chunks (391 here)
#define TILE 2048             // edges per aggregation LDS tile (bucket ~512)
#define ASTRIDE 64            // uints per abuf row
#define SRCMASK 0x07ffffffu   // src in low 27 bits, dstLocal in bits 27..31

typedef __attribute__((ext_vector_type(8))) short short8;
typedef __attribute__((ext_vector_type(4))) float floatx4;

__device__ __forceinline__ ushort f2bf(float f) {
    __hip_bfloat16 h = __float2bfloat16(f);   // RNE
    return *reinterpret_cast<ushort*>(&h);
}

// ---------------------------------------------------------------------------
// K1: [0,B_) hist blocks | [B_,B_+64) weight convert | rest x convert.
// histG layout: [block][bucket] (block-major -> flat scan gives each bin
// block a contiguous output region).  All writes coalesced.  NO fences.
// ---------------------------------------------------------------------------
__global__ __launch_bounds__(256) void prep_kernel(
    const float* __restrict__ x, ushort* __restrict__ xbf, int n4,
    const float* __restrict__ W1, const float* __restrict__ W2,
    const float* __restrict__ b1, const float* __restrict__ b2,
    ushort* __restrict__ w1bf, ushort* __restrict__ w2bf, float* __restrict__ bias,
    const int* __restrict__ dst, int* __restrict__ histG,
    int n_edges, int B_, int nb)
{
    __shared__ int h[NBMAX];
    int bid = blockIdx.x;
    if (bid < B_) {
        for (int j = threadIdx.x; j < nb; j += 256) h[j] = 0;
        __syncthreads();
        int base = bid * CHUNK;
#pragma unroll
        for (int i = 0; i < CHUNK / 256; ++i) {
            int e = base + i * 256 + threadIdx.x;
            if (e < n_edges) atomicAdd(&h[dst[e] >> BSH], 1);
        }
        __syncthreads();
        for (int j = threadIdx.x; j < nb; j += 256)
            histG[bid * nb + j] = h[j];
    } else if (bid < B_ + 64) {
        int i = (bid - B_) * 256 + threadIdx.x;
        if (i < DF * DF) {
            w1bf[i] = f2bf(W1[i]);
            w2bf[i] = f2bf(W2[i]);
        }
        if (i < DF) bias[i] = b1[i] + b2[i];
    } else {
        int i = (bid - B_ - 64) * 256 + threadIdx.x;
        if (i < n4) {
            float4 v = reinterpret_cast<const float4*>(x)[i];
            ushort4 o;
            o.x = f2bf(v.x); o.y = f2bf(v.y); o.z = f2bf(v.z); o.w = f2bf(v.w);
            reinterpret_cast<ushort4*>(xbf)[i] = o;
        }
    }
}

// ---------------------------------------------------------------------------
// K2a: per-1024 exclusive scan over histG (flat, block-major), all linear.
// Writes histS (local-exclusive) + bsum[blk] (block total).  NO fence.
// final_offs(idx) = histS[idx] + bsum_scanned[idx>>10].
// ---------------------------------------------------------------------------
__global__ __launch_bounds__(256) void scan_local_kernel(
    const int* __restrict__ cnt, int* __restrict__ offs,
    int* __restrict__ bsum, int n)
{
    __shared__ int sd[256];
    int t = threadIdx.x;
    int base = blockIdx.x * 1024 + t * 4;

    int4 v = make_int4(0, 0, 0, 0);
    if (base + 3 < n) {
        v = *reinterpret_cast<const int4*>(cnt + base);
    } else {
        if (base + 0 < n) v.x = cnt[base + 0];
        if (base + 1 < n) v.y = cnt[base + 1];
        if (base + 2 < n) v.z = cnt[base + 2];
        if (base + 3 < n) v.w = cnt[base + 3];
    }
    int s = v.x + v.y + v.z + v.w;
    sd[t] = s;
    __syncthreads();
    for (int off = 1; off < 256; off <<= 1) {
        int u = (t >= off) ? sd[t - off] : 0;
        __syncthreads();
        sd[t] += u;
        __syncthreads();
    }
    int incl = sd[t];
    int excl = incl - s;
    if (t == 255) bsum[blockIdx.x] = incl;

    int p0 = excl, p1 = p0 + v.x, p2 = p1 + v.y, p3 = p2 + v.z;
    if (base + 0 < n) offs[base + 0] = p0;
    if (base + 1 < n) offs[base + 1] = p1;
    if (base + 2 < n) offs[base + 2] = p2;
    if (base + 3 < n) offs[base + 3] = p3;
}

// ---------------------------------------------------------------------------
// K2b: single-block exclusive scan of bsum[0..nb2)  (nb2 <= 1024).
// ---------------------------------------------------------------------------
__global__ __launch_bounds__(1024) void scan_bsum_kernel(
    int* __restrict__ bsum, int nb2)
{
    __shared__ int sd[1024];
    int t = threadIdx.x;
    int v = (t < nb2) ? bsum[t] : 0;
    sd[t] = v;
    __syncthreads();
    for (int off = 1; off < 1024; off <<= 1) {
        int u = (t >= off) ? sd[t - off] : 0;
        __syncthreads();
        sd[t] += u;
        __syncthreads();
    }
    if (t < nb2) bsum[t] = sd[t] - v;   // exclusive base per scan block
}

// ---------------------------------------------------------------------------
// K3: bin. Sort this block's CHUNK edges by bucket into LDS, then write its
// OWN CONTIGUOUS region [blk*CHUNK, blk*CHUNK+cnt) with coalesced stores.
// pairs[p] = src | dstLocal<<27.  391 blocks (fat grid), small LDS.
// ---------------------------------------------------------------------------
__global__ __launch_bounds__(256) void bin_kernel(
    const int* __restrict__ src, const int* __restrict__ dst,
    const int* __restrict__ histS, const int* __restrict__ bsum,
    uint* __restrict__ pairs, int n_edges, int B_, int nb)
{
    __shared__ int  cur[NBMAX];     // 6.4 KB global cursors
    __shared__ uint stage[CHUNK];   // 8 KB
    int blk = blockIdx.x;
    for (int j = threadIdx.x; j < nb; j += 256) {
        int idx = blk * nb + j;
        cur[j] = histS[idx] + bsum[idx >> 10];
    }
    __syncthreads();
    int base = blk * CHUNK;
    int cnt = n_edges - base; if (cnt > CHUNK) cnt = CHUNK;
    for (int i = threadIdx.x; i < cnt; i += 256) {
        int e = base + i;
        int d = dst[e];
        int j = d >> BSH;
        int p = atomicAdd(&cur[j], 1);
        stage[p - base] = (uint)src[e] | ((uint)(d & (BNODES - 1)) << 27);
    }
    __syncthreads();
    for (int i = threadIdx.x; i < cnt; i += 256)
        pairs[base + i] = stage[i];
}

// ---------------------------------------------------------------------------
// K4: fused aggregate + MFMA GEMM. Block = 32 nodes = 1 bucket, 256 threads,
// 1563 blocks, 8 blocks/CU (19.9 KB LDS). Runs located via 9-step binary
// search over 391 scanned counts. Wave owns 8 nodes; 16-deep gather.
// ---------------------------------------------------------------------------
__global__ __launch_bounds__(256, 8) void agg_gemm_kernel(
    const ushort* __restrict__ xbf, const uint* __restrict__ pairs,
    const int* __restrict__ histS, const int* __restrict__ bsum,
    const ushort* __restrict__ w1, const ushort* __restrict__ w2,
    const float* __restrict__ bias, float* __restrict__ out,
    int n_nodes, int n_edges, int B_, int nb, int flat)
{
    __shared__ uint sorted[TILE];               // 8 KB (byte offsets, src<<8)
    __shared__ uint abuf[BNODES * ASTRIDE];     // 8 KB
    __shared__ int  rstart[BMAX];               // 1.6 KB
    __shared__ int  rexcl[BMAX + 1];            // 1.6 KB
    __shared__ int hcnt[BNODES];
    __shared__ int hoff[BNODES + 1];
    __shared__ int hcur[BNODES];

    int blk  = blockIdx.x;      // == bucket index
    int node0 = blk * BNODES;
    int wave = threadIdx.x >> 6;
    int lane = threadIdx.x & 63;

    // runs: chunk j's cell for this bucket = [offs(j*nb+blk), offs(j*nb+blk+1))
    for (int j = threadIdx.x; j < B_; j += 256) {
        int idx = j * nb + blk;
        int s = histS[idx] + bsum[idx >> 10];
        int idx2 = idx + 1;
        int e = (idx2 >= flat) ? n_edges : histS[idx2] + bsum[idx2 >> 10];
        rstart[j] = s;
        rexcl[j]  = e - s;     // count (temp)
    }
    __syncthreads();
    if (threadIdx.x < 64) {     // wave 0: exclusive scan of <=448 counts
        int b0 = lane * 7;
        int tv[7];
        int ls = 0;
#pragma unroll
        for (int k = 0; k < 7; ++k) {
            int idx = b0 + k;
            tv[k] = (idx < B_) ? rexcl[idx] : 0;
            ls += tv[k];
        }
        int si = ls;
#pragma unroll
        for (int off = 1; off < 64; off <<= 1) {
            int u = __shfl_up(si, off);
            if (lane >= off) si += u;
        }
        int run = si - ls;
#pragma unroll
        for (int k = 0; k < 7; ++k) {
            int idx = b0 + k;
            if (idx < B_) rexcl[idx] = run;
            run += tv[k];
        }
        if (lane == 63) rexcl[B_] = run;   // total
    }
    __syncthreads();
    int total = rexcl[B_];

    const char* xu = (const char*)xbf;
    uint lane4 = (uint)lane << 2;

    float2 acc[8];
#pragma unroll
    for (int i = 0; i < 8; ++i) acc[i] = make_float2(0.f, 0.f);

    for (int t0 = 0; t0 < total; t0 += TILE) {
        int cnt = total - t0; if (cnt > TILE) cnt = TILE;

        if (threadIdx.x < BNODES) hcnt[threadIdx.x] = 0;
        __syncthreads();

        // pass A: binary-search run, read pair into registers, node-histogram
        uint pk_[TILE / 256];
#pragma unroll
        for (int k = 0; k < TILE / 256; ++k) {
            int i = threadIdx.x + k * 256;
            if (i < cnt) {
                int t = t0 + i;
                int lo = 0, hi = B_;
                while (lo + 1 < hi) {
                    int mid = (lo + hi) >> 1;
                    if (rexcl[mid] <= t) lo = mid; else hi = mid;
                }
                uint pk = pairs[rstart[lo] + (t - rexcl[lo])];
                pk_[k] = pk;
                atomicAdd(&hcnt[pk >> 27], 1);
            }
        }
        __syncthreads();

        // 32-entry exclusive scan by wave 0 via shfl
        if (threadIdx.x < 64) {
            int v = (lane < BNODES) ? hcnt[lane] : 0;
#pragma unroll
            for (int off = 1; off < BNODES; off <<= 1) {
                int u = __shfl_up(v, off);
                if (lane >= off) v += u;
            }
            if (lane < BNODES) {
                hoff[lane + 1] = v;
                hcur[lane] = v - hcnt[lane];
            }
            if (lane == 0) hoff[0] = 0;
        }
        __syncthreads();

        // pass B: scatter pre-scaled row byte-offsets, node-sorted
#pragma unroll
        for (int k = 0; k < TILE / 256; ++k) {
            int i = threadIdx.x + k * 256;
            if (i < cnt) {
                uint pk = pk_[k];
                int p = atomicAdd(&hcur[pk >> 27], 1);
                sorted[p] = (pk & SRCMASK) << 8;   // byte offset of 256B row
            }
        }
        __syncthreads();

        // wave owns nodes wave*8 .. wave*8+7; 16-deep independent gathers
#pragma unroll
        for (int i = 0; i < 8; ++i) {
            int nl = wave * 8 + i;
            int j0 = hoff[nl], j1 = hoff[nl + 1];
            float2 a = acc[i];
            int j = j0;
            for (; j + 15 < j1; j += 16) {
                uint u[16];
#pragma unroll
                for (int k = 0; k < 16; ++k)
                    u[k] = *(const uint*)(xu + (size_t)(sorted[j + k] + lane4));
#pragma unroll
                for (int k = 0; k < 16; ++k) {
                    a.x += __uint_as_float(u[k] << 16);
                    a.y += __uint_as_float(u[k] & 0xffff0000u);
                }
            }
            for (; j + 3 < j1; j += 4) {
                uint u0 = *(const uint*)(xu + (size_t)(sorted[j + 0] + lane4));
                uint u1 = *(const uint*)(xu + (size_t)(sorted[j + 1] + lane4));
                uint u2 = *(const uint*)(xu + (size_t)(sorted[j + 2] + lane4));
                uint u3 = *(const uint*)(xu + (size_t)(sorted[j + 3] + lane4));
                a.x += __uint_as_float(u0 << 16) + __uint_as_float(u1 << 16)
                     + __uint_as_float(u2 << 16) + __uint_as_float(u3 << 16);
                a.y += __uint_as_float(u0 & 0xffff0000u) + __uint_as_float(u1 & 0xffff0000u)
                     + __uint_as_float(u2 & 0xffff0000u) + __uint_as_float(u3 & 0xffff0000u);
            }
            for (; j < j1; ++j) {
                uint u = *(const uint*)(xu + (size_t)(sorted[j] + lane4));
                a.x += __uint_as_float(u << 16);
                a.y += __uint_as_float(u & 0xffff0000u);
            }
            acc[i] = a;
        }
        __syncthreads();   // protect sorted/hist before next tile
    }

    // stage aggregated rows as bf16 into LDS
#pragma unroll
    for (int i = 0; i < 8; ++i) {
        int nl = wave * 8 + i;
        abuf[nl * ASTRIDE + lane] =
            (uint)f2bf(acc[i].x) | ((uint)f2bf(acc[i].y) << 16);
    }
    __syncthreads();

    // ---- MFMA phase: 2 waves per 16-row group; each does 4 of 8 o-tiles ----
    int quad = lane >> 4;
    int m    = lane & 15;
    int rg   = wave >> 1;          // row group 0..1
    int half = wave & 1;           // which 4 o-tiles
    int rowL = rg * 16 + m;
    int rowG = node0 + rowL;
    int rowC = (rowG < n_nodes) ? rowG : (n_nodes - 1);   // clamp loads

    short8 xa[4], aa[4];
#pragma unroll
    for (int ks = 0; ks < 4; ++ks) {
        xa[ks] = *reinterpret_cast<const short8*>(xbf + (size_t)rowC * DF + ks * 32 + quad * 8);
        aa[ks] = *reinterpret_cast<const short8*>(&abuf[rowL * ASTRIDE + ks * 16 + quad * 4]);
    }

    int nbase = node0 + rg * 16;
#pragma unroll
    for (int oi = 0; oi < 4; ++oi) {
        int ot = half * 4 + oi;
        int o = ot * 16 + m;
        floatx4 c = {0.f, 0.f, 0.f, 0.f};
#pragma unroll
        for (int ks = 0; ks < 4; ++ks) {
            short8 bf1 = *reinterpret_cast<const short8*>(w1 + (size_t)o * DF + ks * 32 + quad * 8);
            short8 bf2 = *reinterpret_cast<const short8*>(w2 + (size_t)o * DF + ks * 32 + quad * 8);
            c = __builtin_amdgcn_mfma_f32_16x16x32_bf16(xa[ks], bf1, c, 0, 0, 0);
            c = __builtin_amdgcn_mfma_f32_16x16x32_bf16(aa[ks], bf2, c, 0, 0, 0);
        }
        float bv = bias[o];
#pragma unroll
        for (int r = 0; r < 4; ++r) {
            int row = nbase + quad * 4 + r;
            if (row < n_nodes) out[(size_t)row * DF + o] = c[r] + bv;
        }
    }
}

extern "C" void kernel_launch(void* const* d_in, const int* in_sizes, int n_in,
                              void* d_out, int out_size, void* d_ws, size_t ws_size,
                              hipStream_t stream) {
    const float* x  = (const float*)d_in[0];
    const float* W1 = (const float*)d_in[1];
    const float* b1 = (const float*)d_in[2];
    const float* W2 = (const float*)d_in[3];
    const float* b2 = (const float*)d_in[4];
    const int* esrc = (const int*)d_in[5];
    const int* edst = (const int*)d_in[6];
    float* out = (float*)d_out;

    int n_nodes = in_sizes[0] / DF;
    int n_edges = in_sizes[5];

    int nb = (n_nodes + BNODES - 1) >> BSH;       // buckets (1563)
    int B_ = (n_edges + CHUNK - 1) / CHUNK;       // edge chunks (391 <= BMAX-1)
    int flat = nb * B_;                           // hist matrix size (~611k)

    auto rnd16 = [](size_t v) { return (v + 15) & ~(size_t)15; };

    char* ws = (char*)d_ws;
    ushort* xbf   = (ushort*)ws;                 ws += rnd16((size_t)n_nodes * DF * 2);
    ushort* w1bf  = (ushort*)ws;                 ws += rnd16((size_t)DF * DF * 2);
    ushort* w2bf  = (ushort*)ws;                 ws += rnd16((size_t)DF * DF * 2);
    float*  bias  = (float*)ws;                  ws += rnd16((size_t)DF * 4);
    int*    histG = (int*)ws;                    ws += rnd16((size_t)flat * 4);
    int*    histS = (int*)ws;                    ws += rnd16((size_t)(flat + 1) * 4);
    int*    bsum  = (int*)ws;                    ws += 1024 * 4;
    uint*   pairs = (uint*)ws;

    int n4 = n_nodes * DF / 4;
    int prep_blocks = B_ + 64 + (n4 + 255) / 256;
    prep_kernel<<<prep_blocks, 256, 0, stream>>>(
        x, xbf, n4, W1, W2, b1, b2, w1bf, w2bf, bias,
        edst, histG, n_edges, B_, nb);

    int nb2 = (flat + 1023) / 1024;
    scan_local_kernel<<<nb2, 256, 0, stream>>>(histG, histS, bsum, flat);
    scan_bsum_kernel<<<1, 1024, 0, stream>>>(bsum, nb2);

    bin_kernel<<<B_, 256, 0, stream>>>(esrc, edst, histS, bsum, pairs, n_edges, B_, nb);

    agg_gemm_kernel<<<nb, 256, 0, stream>>>(
        xbf, pairs, histS, bsum, w1bf, w2bf, bias, out,
        n_nodes, n_edges, B_, nb, flat);
}

// Round 7
// 152.146 us; speedup vs baseline: 2.3210x; 1.0894x over previous
//
#include <hip/hip_runtime.h>
#include <hip/hip_bf16.h>

#define DF 128
#define BSH 5                 // bucket = dst >> 5  (32 nodes / bucket)
#define BNODES 32
#define NBMAX 1600            // max buckets (50000/32 = 1563)
#define CHUNK 2048            // edges per fused hist/sort block (391 blocks)
#define BMAX 400              // max edge chunks (391 here)
#define TILE 2048             // edges per aggregation LDS tile (bucket ~512)
#define ASTRIDE 64            // uints per abuf row
#define SRCMASK 0x07ffffffu   // src in low 27 bits, dstLocal in bits 27..31

typedef __attribute__((ext_vector_type(8))) short short8;
typedef __attribute__((ext_vector_type(4))) float floatx4;

__device__ __forceinline__ ushort f2bf(float f) {
    __hip_bfloat16 h = __float2bfloat16(f);   // RNE
    return *reinterpret_cast<ushort*>(&h);
}

// ---------------------------------------------------------------------------
// K1: [0,B_) fused hist+scan+sort blocks | [B_,B_+64) weight convert |
// rest x convert.
// Key insight: with block-major pairs layout, chunk j's output region starts
// at exactly j*CHUNK, and the within-region layout depends ONLY on chunk j's
// own histogram prefix. So each edge block independently: histograms its
// 2048 edges, scans the 1563-bucket row in-block, writes the row prefix to
// rowoffs[j][*] (for agg), sorts edges by bucket into LDS, and writes its
// contiguous pairs region coalesced. No global scan, no cross-block coupling.
// ---------------------------------------------------------------------------
__global__ __launch_bounds__(256) void prep_kernel(
    const float* __restrict__ x, ushort* __restrict__ xbf, int n4,
    const float* __restrict__ W1, const float* __restrict__ W2,
    const float* __restrict__ b1, const float* __restrict__ b2,
    ushort* __restrict__ w1bf, ushort* __restrict__ w2bf, float* __restrict__ bias,
    const int* __restrict__ src, const int* __restrict__ dst,
    int* __restrict__ rowoffs, uint* __restrict__ pairs,
    int n_edges, int B_, int nb)
{
    __shared__ int  h[NBMAX];       // hist -> prefix -> cursors (6.4 KB)
    __shared__ int  sd[256];
    __shared__ uint stage[CHUNK];   // 8 KB
    int bid = blockIdx.x;
    int tid = threadIdx.x;

    if (bid < B_) {
        int base = bid * CHUNK;
        int cnt = n_edges - base; if (cnt > CHUNK) cnt = CHUNK;

        for (int j = tid; j < nb; j += 256) h[j] = 0;
        __syncthreads();

        // load edges to regs + LDS histogram
        int d[CHUNK / 256], s[CHUNK / 256];
#pragma unroll
        for (int k = 0; k < CHUNK / 256; ++k) {
            int i = k * 256 + tid;
            bool ok = i < cnt;
            d[k] = ok ? dst[base + i] : -1;
            s[k] = ok ? src[base + i] : 0;
            if (ok) atomicAdd(&h[d[k] >> BSH], 1);
        }
        __syncthreads();

        // in-block exclusive scan of nb+1 entries (thread t owns 7)
        int b0 = tid * 7;
        int tv[7];
        int ls = 0;
#pragma unroll
        for (int k = 0; k < 7; ++k) {
            int idx = b0 + k;
            tv[k] = (idx < nb) ? h[idx] : 0;
            ls += tv[k];
        }
        sd[tid] = ls;
        __syncthreads();
        for (int off = 1; off < 256; off <<= 1) {
            int u = (tid >= off) ? sd[tid - off] : 0;
            __syncthreads();
            sd[tid] += u;
            __syncthreads();
        }
        int run = sd[tid] - ls;

        // write prefix: LDS cursors + global rowoffs row (incl. entry nb = cnt)
        int* ro = rowoffs + (size_t)bid * (nb + 1);
#pragma unroll
        for (int k = 0; k < 7; ++k) {
            int idx = b0 + k;
            if (idx < nb) h[idx] = run;
            if (idx <= nb) ro[idx] = run;
            run += tv[k];
        }
        __syncthreads();   // prefix stable before cursor atomics

        // sort into LDS stage, then coalesced write of own region
#pragma unroll
        for (int k = 0; k < CHUNK / 256; ++k) {
            if (d[k] >= 0) {
                int p = atomicAdd(&h[d[k] >> BSH], 1);
                stage[p] = (uint)s[k] | ((uint)(d[k] & (BNODES - 1)) << 27);
            }
        }
        __syncthreads();
        for (int i = tid; i < cnt; i += 256)
            pairs[base + i] = stage[i];
    } else if (bid < B_ + 64) {
        int i = (bid - B_) * 256 + tid;
        if (i < DF * DF) {
            w1bf[i] = f2bf(W1[i]);
            w2bf[i] = f2bf(W2[i]);
        }
        if (i < DF) bias[i] = b1[i] + b2[i];
    } else {
        int i = (bid - B_ - 64) * 256 + tid;
        if (i < n4) {
            float4 v = reinterpret_cast<const float4*>(x)[i];
            ushort4 o;
            o.x = f2bf(v.x); o.y = f2bf(v.y); o.z = f2bf(v.z); o.w = f2bf(v.w);
            reinterpret_cast<ushort4*>(xbf)[i] = o;
        }
    }
}

// ---------------------------------------------------------------------------
// K2: fused aggregate + MFMA GEMM. Block = 32 nodes = 1 bucket, 256 threads,
// 1563 blocks, 8 blocks/CU (~19.6 KB LDS). Run j for bucket blk:
// start = j*CHUNK + rowoffs[j][blk], count = rowoffs[j][blk+1]-rowoffs[j][blk].
// 9-step binary search locates run per tile element. 16-deep gather. MFMA.
// ---------------------------------------------------------------------------
__global__ __launch_bounds__(256, 8) void agg_gemm_kernel(
    const ushort* __restrict__ xbf, const uint* __restrict__ pairs,
    const int* __restrict__ rowoffs,
    const ushort* __restrict__ w1, const ushort* __restrict__ w2,
    const float* __restrict__ bias, float* __restrict__ out,
    int n_nodes, int B_, int nb)
{
    __shared__ uint sorted[TILE];               // 8 KB (byte offsets, src<<8)
    __shared__ uint abuf[BNODES * ASTRIDE];     // 8 KB
    __shared__ int  rstart[BMAX];               // 1.6 KB
    __shared__ int  rexcl[BMAX + 1];            // 1.6 KB
    __shared__ int hcnt[BNODES];
    __shared__ int hoff[BNODES + 1];
    __shared__ int hcur[BNODES];

    int blk  = blockIdx.x;      // == bucket index
    int node0 = blk * BNODES;
    int wave = threadIdx.x >> 6;
    int lane = threadIdx.x & 63;
    int NBP = nb + 1;

    // runs: chunk j's cell for this bucket (independent per-row offsets)
    for (int j = threadIdx.x; j < B_; j += 256) {
        const int* ro = rowoffs + (size_t)j * NBP + blk;
        int s = ro[0];
        int e = ro[1];
        rstart[j] = j * CHUNK + s;
        rexcl[j]  = e - s;     // count (temp)
    }
    __syncthreads();
    if (threadIdx.x < 64) {     // wave 0: exclusive scan of <=448 counts
        int b0 = lane * 7;
        int tv[7];
        int ls = 0;
#pragma unroll
        for (int k = 0; k < 7; ++k) {
            int idx = b0 + k;
            tv[k] = (idx < B_) ? rexcl[idx] : 0;
            ls += tv[k];
        }
        int si = ls;
#pragma unroll
        for (int off = 1; off < 64; off <<= 1) {
            int u = __shfl_up(si, off);
            if (lane >= off) si += u;
        }
        int run = si - ls;
#pragma unroll
        for (int k = 0; k < 7; ++k) {
            int idx = b0 + k;
            if (idx < B_) rexcl[idx] = run;
            run += tv[k];
        }
        if (lane == 63) rexcl[B_] = run;   // total
    }
    __syncthreads();
    int total = rexcl[B_];

    const char* xu = (const char*)xbf;
    uint lane4 = (uint)lane << 2;

    float2 acc[8];
#pragma unroll
    for (int i = 0; i < 8; ++i) acc[i] = make_float2(0.f, 0.f);

    for (int t0 = 0; t0 < total; t0 += TILE) {
        int cnt = total - t0; if (cnt > TILE) cnt = TILE;

        if (threadIdx.x < BNODES) hcnt[threadIdx.x] = 0;
        __syncthreads();

        // pass A: binary-search run, read pair into registers, node-histogram
        uint pk_[TILE / 256];
#pragma unroll
        for (int k = 0; k < TILE / 256; ++k) {
            int i = threadIdx.x + k * 256;
            if (i < cnt) {
                int t = t0 + i;
                int lo = 0, hi = B_;
                while (lo + 1 < hi) {
                    int mid = (lo + hi) >> 1;
                    if (rexcl[mid] <= t) lo = mid; else hi = mid;
                }
                uint pk = pairs[rstart[lo] + (t - rexcl[lo])];
                pk_[k] = pk;
                atomicAdd(&hcnt[pk >> 27], 1);
            }
        }
        __syncthreads();

        // 32-entry exclusive scan by wave 0 via shfl
        if (threadIdx.x < 64) {
            int v = (lane < BNODES) ? hcnt[lane] : 0;
#pragma unroll
            for (int off = 1; off < BNODES; off <<= 1) {
                int u = __shfl_up(v, off);
                if (lane >= off) v += u;
            }
            if (lane < BNODES) {
                hoff[lane + 1] = v;
                hcur[lane] = v - hcnt[lane];
            }
            if (lane == 0) hoff[0] = 0;
        }
        __syncthreads();

        // pass B: scatter pre-scaled row byte-offsets, node-sorted
#pragma unroll
        for (int k = 0; k < TILE / 256; ++k) {
            int i = threadIdx.x + k * 256;
            if (i < cnt) {
                uint pk = pk_[k];
                int p = atomicAdd(&hcur[pk >> 27], 1);
                sorted[p] = (pk & SRCMASK) << 8;   // byte offset of 256B row
            }
        }
        __syncthreads();

        // wave owns nodes wave*8 .. wave*8+7; 16-deep independent gathers
#pragma unroll
        for (int i = 0; i < 8; ++i) {
            int nl = wave * 8 + i;
            int j0 = hoff[nl], j1 = hoff[nl + 1];
            float2 a = acc[i];
            int j = j0;
            for (; j + 15 < j1; j += 16) {
                uint u[16];
#pragma unroll
                for (int k = 0; k < 16; ++k)
                    u[k] = *(const uint*)(xu + (size_t)(sorted[j + k] + lane4));
#pragma unroll
                for (int k = 0; k < 16; ++k) {
                    a.x += __uint_as_float(u[k] << 16);
                    a.y += __uint_as_float(u[k] & 0xffff0000u);
                }
            }
            for (; j + 3 < j1; j += 4) {
                uint u0 = *(const uint*)(xu + (size_t)(sorted[j + 0] + lane4));
                uint u1 = *(const uint*)(xu + (size_t)(sorted[j + 1] + lane4));
                uint u2 = *(const uint*)(xu + (size_t)(sorted[j + 2] + lane4));
                uint u3 = *(const uint*)(xu + (size_t)(sorted[j + 3] + lane4));
                a.x += __uint_as_float(u0 << 16) + __uint_as_float(u1 << 16)
                     + __uint_as_float(u2 << 16) + __uint_as_float(u3 << 16);
                a.y += __uint_as_float(u0 & 0xffff0000u) + __uint_as_float(u1 & 0xffff0000u)
                     + __uint_as_float(u2 & 0xffff0000u) + __uint_as_float(u3 & 0xffff0000u);
            }
            for (; j < j1; ++j) {
                uint u = *(const uint*)(xu + (size_t)(sorted[j] + lane4));
                a.x += __uint_as_float(u << 16);
                a.y += __uint_as_float(u & 0xffff0000u);
            }
            acc[i] = a;
        }
        __syncthreads();   // protect sorted/hist before next tile
    }

    // stage aggregated rows as bf16 into LDS
#pragma unroll
    for (int i = 0; i < 8; ++i) {
        int nl = wave * 8 + i;
        abuf[nl * ASTRIDE + lane] =
            (uint)f2bf(acc[i].x) | ((uint)f2bf(acc[i].y) << 16);
    }
    __syncthreads();

    // ---- MFMA phase: 2 waves per 16-row group; each does 4 of 8 o-tiles ----
    int quad = lane >> 4;
    int m    = lane & 15;
    int rg   = wave >> 1;          // row group 0..1
    int half = wave & 1;           // which 4 o-tiles
    int rowL = rg * 16 + m;
    int rowG = node0 + rowL;
    int rowC = (rowG < n_nodes) ? rowG : (n_nodes - 1);   // clamp loads

    short8 xa[4], aa[4];
#pragma unroll
    for (int ks = 0; ks < 4; ++ks) {
        xa[ks] = *reinterpret_cast<const short8*>(xbf + (size_t)rowC * DF + ks * 32 + quad * 8);
        aa[ks] = *reinterpret_cast<const short8*>(&abuf[rowL * ASTRIDE + ks * 16 + quad * 4]);
    }

    int nbase = node0 + rg * 16;
#pragma unroll
    for (int oi = 0; oi < 4; ++oi) {
        int ot = half * 4 + oi;
        int o = ot * 16 + m;
        floatx4 c = {0.f, 0.f, 0.f, 0.f};
#pragma unroll
        for (int ks = 0; ks < 4; ++ks) {
            short8 bf1 = *reinterpret_cast<const short8*>(w1 + (size_t)o * DF + ks * 32 + quad * 8);
            short8 bf2 = *reinterpret_cast<const short8*>(w2 + (size_t)o * DF + ks * 32 + quad * 8);
            c = __builtin_amdgcn_mfma_f32_16x16x32_bf16(xa[ks], bf1, c, 0, 0, 0);
            c = __builtin_amdgcn_mfma_f32_16x16x32_bf16(aa[ks], bf2, c, 0, 0, 0);
        }
        float bv = bias[o];
#pragma unroll
        for (int r = 0; r < 4; ++r) {
            int row = nbase + quad * 4 + r;
            if (row < n_nodes) out[(size_t)row * DF + o] = c[r] + bv;
        }
    }
}

extern "C" void kernel_launch(void* const* d_in, const int* in_sizes, int n_in,
                              void* d_out, int out_size, void* d_ws, size_t ws_size,
                              hipStream_t stream) {
    const float* x  = (const float*)d_in[0];
    const float* W1 = (const float*)d_in[1];
    const float* b1 = (const float*)d_in[2];
    const float* W2 = (const float*)d_in[3];
    const float* b2 = (const float*)d_in[4];
    const int* esrc = (const int*)d_in[5];
    const int* edst = (const int*)d_in[6];
    float* out = (float*)d_out;

    int n_nodes = in_sizes[0] / DF;
    int n_edges = in_sizes[5];

    int nb = (n_nodes + BNODES - 1) >> BSH;       // buckets (1563)
    int B_ = (n_edges + CHUNK - 1) / CHUNK;       // edge chunks (391 <= BMAX-1)

    auto rnd16 = [](size_t v) { return (v + 15) & ~(size_t)15; };

    char* ws = (char*)d_ws;
    ushort* xbf     = (ushort*)ws;               ws += rnd16((size_t)n_nodes * DF * 2);
    ushort* w1bf    = (ushort*)ws;               ws += rnd16((size_t)DF * DF * 2);
    ushort* w2bf    = (ushort*)ws;               ws += rnd16((size_t)DF * DF * 2);
    float*  bias    = (float*)ws;                ws += rnd16((size_t)DF * 4);
    int*    rowoffs = (int*)ws;                  ws += rnd16((size_t)B_ * (nb + 1) * 4);
    uint*   pairs   = (uint*)ws;

    int n4 = n_nodes * DF / 4;
    int prep_blocks = B_ + 64 + (n4 + 255) / 256;
    prep_kernel<<<prep_blocks, 256, 0, stream>>>(
        x, xbf, n4, W1, W2, b1, b2, w1bf, w2bf, bias,
        esrc, edst, rowoffs, pairs, n_edges, B_, nb);

    agg_gemm_kernel<<<nb, 256, 0, stream>>>(
        xbf, pairs, rowoffs, w1bf, w2bf, bias, out, n_nodes, B_, nb);
}